// Round 5
// baseline (10160.533 us; speedup 1.0000x reference)
//
#include <hip/hip_runtime.h>

#define Bb 128
#define Tt 512
#define Vv 96
#define Hh 512
#define OUT_H 6291456
#define OUT_C 6488064

typedef _Float16 f16x4 __attribute__((ext_vector_type(4)));
typedef _Float16 f16x8 __attribute__((ext_vector_type(8)));
typedef float f32x4 __attribute__((ext_vector_type(4)));

struct KP {
  const float *x, *h0, *c0;
  const float *Wih0, *Whh0, *bih0, *bhh0;
  const float *Wih1, *Whh1, *bih1, *bhh1;
  const float *Wih2, *Whh2, *bih2, *bhh2;
  const float *Wfc, *bfc;
  float* out;
  unsigned* bar;     // gc[l] at bar[l*32] (cell groups), fc at bar[96]; monotone
  float* fbias;      // [3][2048] fused gate biases + [96] fc bias
  _Float16* wimg;    // [98][65536] per-block pre-swizzled LDS images
  _Float16* xb;      // [Bb][Tt][Vv] f16 input
  _Float16* hring;   // [3][8][Bb][Hh] f16 h ring, depth 8; h0 in slot 7
};

__device__ __forceinline__ float sigf(float x) { return 1.f / (1.f + __expf(-x)); }

// Device-coherent (MALL, sc1) relaxed accessors — no wbl2/inv cache maintenance.
__device__ __forceinline__ f16x4 ld_dc_f16x4(const _Float16* p) {
  unsigned long long u = __hip_atomic_load((const unsigned long long*)p, __ATOMIC_RELAXED, __HIP_MEMORY_SCOPE_AGENT);
  union { unsigned long long u; f16x4 f; } c; c.u = u; return c.f;
}
__device__ __forceinline__ void st_dc_u32(unsigned* p, unsigned v) {
  __hip_atomic_store(p, v, __ATOMIC_RELAXED, __HIP_MEMORY_SCOPE_AGENT);
}
__device__ __forceinline__ void wait_ge(unsigned* p, unsigned v) {
  int guard = 0;
  while (__hip_atomic_load(p, __ATOMIC_RELAXED, __HIP_MEMORY_SCOPE_AGENT) < v) {
    if (++guard > 200000) break;   // broken flags terminate; absmax diagnoses
    __builtin_amdgcn_s_sleep(1);
  }
}

// acc += A[128 x 16K] * W^T from LDS ([NF*16 rows][512] f16, XOR swizzle).
// 8 waves split M (wave w owns rows w*16..w*16+15). sc1 A loads, 8-deep batches.
template <int KSTEPS, int LSTRIDE, bool SWZ, int NF, bool DC>
__device__ __forceinline__ void gemm1(const _Float16* __restrict__ Abase, int astride,
                                      const _Float16* lds, f32x4 (&acc)[NF]) {
  const int lane = threadIdx.x & 63;
  const int w = threadIdx.x >> 6;
  const int l15 = lane & 15, l4 = lane >> 4;
  const _Float16* ap = Abase + (w * 16 + l15) * astride + l4 * 4;
#pragma unroll
  for (int kb = 0; kb < (KSTEPS + 7) / 8; ++kb) {
    f16x4 av[8];
#pragma unroll
    for (int i = 0; i < 8; ++i)
      if (kb * 8 + i < KSTEPS) {
        const _Float16* p = ap + (kb * 8 + i) * 16;
        av[i] = DC ? ld_dc_f16x4(p) : *(const f16x4*)p;
      }
#pragma unroll
    for (int i = 0; i < 8; ++i)
      if (kb * 8 + i < KSTEPS) {
        const int kk = (kb * 8 + i) * 16;
#pragma unroll
        for (int n = 0; n < NF; ++n) {
          const int r = n * 16 + l15;
          int idx = r * LSTRIDE + kk + l4 * 4;
          if (SWZ) idx ^= (r & 7) << 3;
          f16x4 bv = *(const f16x4*)(lds + idx);
          acc[n] = __builtin_amdgcn_mfma_f32_16x16x16f16(av[i], bv, acc[n], 0, 0, 0);
        }
      }
  }
}

// Fused dual-GEMM: acc += A1*B1^T + A2*B2^T, both sc1, 16 loads in flight.
template <int NF>
__device__ __forceinline__ void gemm2(const _Float16* __restrict__ A1,
                                      const _Float16* __restrict__ A2,
                                      const _Float16* lds1, const _Float16* lds2,
                                      f32x4 (&acc)[NF]) {
  const int lane = threadIdx.x & 63;
  const int w = threadIdx.x >> 6;
  const int l15 = lane & 15, l4 = lane >> 4;
  const _Float16* ap1 = A1 + (w * 16 + l15) * 512 + l4 * 4;
  const _Float16* ap2 = A2 + (w * 16 + l15) * 512 + l4 * 4;
#pragma unroll
  for (int kb = 0; kb < 4; ++kb) {
    f16x4 av1[8], av2[8];
#pragma unroll
    for (int i = 0; i < 8; ++i) av1[i] = ld_dc_f16x4(ap1 + (kb * 8 + i) * 16);
#pragma unroll
    for (int i = 0; i < 8; ++i) av2[i] = ld_dc_f16x4(ap2 + (kb * 8 + i) * 16);
#pragma unroll
    for (int i = 0; i < 8; ++i) {
      const int kk = (kb * 8 + i) * 16;
#pragma unroll
      for (int n = 0; n < NF; ++n) {
        const int r = n * 16 + l15;
        int idx = (r * 512 + kk + l4 * 4) ^ ((r & 7) << 3);
        f16x4 b1 = *(const f16x4*)(lds1 + idx);
        acc[n] = __builtin_amdgcn_mfma_f32_16x16x16f16(av1[i], b1, acc[n], 0, 0, 0);
      }
    }
#pragma unroll
    for (int i = 0; i < 8; ++i) {
      const int kk = (kb * 8 + i) * 16;
#pragma unroll
      for (int n = 0; n < NF; ++n) {
        const int r = n * 16 + l15;
        int idx = (r * 512 + kk + l4 * 4) ^ ((r & 7) << 3);
        f16x4 b2 = *(const f16x4*)(lds2 + idx);
        acc[n] = __builtin_amdgcn_mfma_f32_16x16x16f16(av2[i], b2, acc[n], 0, 0, 0);
      }
    }
  }
}

__global__ __launch_bounds__(256) void prologue_kernel(KP A) {
  const int tid = threadIdx.x, bid = blockIdx.x;
  const int gt = bid * 256 + tid, gn = 98 * 256;
  for (int i = gt; i < Bb * Tt * Vv; i += gn) A.xb[i] = (_Float16)A.x[i];
  for (int i = gt; i < 3 * Bb * Hh; i += gn) {
    int l = i >> 16, rem = i & 65535;
    A.hring[(l * 8 + 7) * (Bb * Hh) + rem] = (_Float16)A.h0[i];
  }
  for (int i = gt; i < 3 * 2048; i += gn) {
    int l = i >> 11, c = i & 2047;
    const float* bi = (l == 0) ? A.bih0 : (l == 1) ? A.bih1 : A.bih2;
    const float* bh = (l == 0) ? A.bhh0 : (l == 1) ? A.bhh1 : A.bhh2;
    A.fbias[i] = bi[c] + bh[c];
  }
  for (int i = gt; i < Vv; i += gn) A.fbias[3 * 2048 + i] = A.bfc[i];

  _Float16* img = A.wimg + (size_t)bid * 65536;
  if (bid < 96) {
    const int l = bid >> 5, j0 = (bid & 31) * 16;
    const float* Wh = (l == 0) ? A.Whh0 : (l == 1) ? A.Whh1 : A.Whh2;
    for (int e = tid; e < 64 * 512; e += 256) {   // W_hh slice, rows = gate*16+col
      int r = e >> 9, k = e & 511;
      img[(r * 512 + k) ^ ((r & 7) << 3)] = (_Float16)Wh[((r >> 4) * 512 + j0 + (r & 15)) * Hh + k];
    }
    if (l == 0) {
      for (int e = tid; e < 64 * 96; e += 256) {
        int r = e / 96, k = e - r * 96;
        img[32768 + r * 104 + k] = (_Float16)A.Wih0[((r >> 4) * 512 + j0 + (r & 15)) * Vv + k];
      }
    } else {
      const float* Wi = (l == 1) ? A.Wih1 : A.Wih2;
      for (int e = tid; e < 64 * 512; e += 256) {
        int r = e >> 9, k = e & 511;
        img[32768 + ((r * 512 + k) ^ ((r & 7) << 3))] = (_Float16)Wi[((r >> 4) * 512 + j0 + (r & 15)) * Hh + k];
      }
    }
  } else {
    const int nt = bid - 96;
    for (int e = tid; e < 48 * 512; e += 256) {
      int r = e >> 9, k = e & 511;
      img[(r * 512 + k) ^ ((r & 7) << 3)] = (_Float16)A.Wfc[(nt * 48 + r) * Hh + k];
    }
  }
}

__global__ __launch_bounds__(512) void lstm_persist(KP A) {
  __shared__ _Float16 wlds[65536];  // 128 KB: [0..32768) W_hh/W_fc, [32768..) W_ih
  const int tid = threadIdx.x, bid = blockIdx.x;
  const int lane = tid & 63, w = tid >> 6;
  const int l15 = lane & 15, l4 = lane >> 4;
  unsigned* gc = A.bar;

  const bool isfc = (bid >= 96);
  const int l = isfc ? 2 : (bid >> 5);
  const int j0 = isfc ? 0 : (bid & 31) * 16;
  const int nt = isfc ? bid - 96 : 0;

  {  // stage pre-swizzled weight image ONCE
    const f16x8* src = (const f16x8*)(A.wimg + (size_t)bid * 65536);
    f16x8* dst = (f16x8*)wlds;
    const int cnt = isfc ? 3072 : 8192;
    for (int e = tid; e < cnt; e += 512) dst[e] = src[e];
  }

  if (!isfc) {
    float biasr[4], creg[4];
#pragma unroll
    for (int n = 0; n < 4; ++n) biasr[n] = A.fbias[l * 2048 + n * 512 + j0 + l15];
#pragma unroll
    for (int q = 0; q < 4; ++q)
      creg[q] = A.c0[l * (Bb * Hh) + (w * 16 + l4 * 4 + q) * Hh + j0 + l15];
    __syncthreads();

    for (int t = 0; t < Tt; ++t) {
      if (tid == 0) {
        if (l > 0) wait_ge(&gc[(l - 1) * 32], 32u * (unsigned)(t + 1));  // producer h_{l-1}(t)
        if (t > 0) wait_ge(&gc[l * 32], 32u * (unsigned)t);              // own group h_l(t-1)
        if (t >= 8) {                                                    // ring overwrite guard
          if (l < 2) wait_ge(&gc[(l + 1) * 32], 32u * (unsigned)(t - 7));
          else       wait_ge(&gc[96], 2u * (unsigned)(t - 7));
        }
      }
      __syncthreads();

      f32x4 acc[4] = {};
      const _Float16* hprev = A.hring + (size_t)(l * 8 + ((t - 1) & 7)) * (Bb * Hh);
      if (l == 0) {
        gemm1<6, 104, false, 4, false>(A.xb + t * Vv, Tt * Vv, wlds + 32768, acc);
        gemm1<32, 512, true, 4, true>(hprev, Hh, wlds, acc);
      } else {
        const _Float16* hin = A.hring + (size_t)((l - 1) * 8 + (t & 7)) * (Bb * Hh);
        gemm2<4>(hin, hprev, wlds + 32768, wlds, acc);
      }

      _Float16* rp = A.hring + (size_t)(l * 8 + (t & 7)) * (Bb * Hh);
      const int j = j0 + l15;
#pragma unroll
      for (int q = 0; q < 4; ++q) {
        const int b = w * 16 + l4 * 4 + q;
        float gi = acc[0][q] + biasr[0];
        float gf = acc[1][q] + biasr[1];
        float gg = acc[2][q] + biasr[2];
        float go = acc[3][q] + biasr[3];
        float iv = sigf(gi), fv = sigf(gf), gv = tanhf(gg), ov = sigf(go);
        float cn = fv * creg[q] + iv * gv;
        creg[q] = cn;
        float hv = ov * tanhf(cn);
        union { _Float16 h; unsigned short u; } cv; cv.h = (_Float16)hv;
        unsigned hb = cv.u;
        unsigned ob = (unsigned)__shfl_xor((int)hb, 1, 64);
        if ((l15 & 1) == 0) st_dc_u32((unsigned*)(rp + b * Hh + j), hb | (ob << 16));
        if (t == Tt - 1) {
          A.out[OUT_H + (l * Bb + b) * Hh + j] = hv;
          A.out[OUT_C + (l * Bb + b) * Hh + j] = cn;
        }
      }
      __syncthreads();   // drain vmcnt: sc1 stores at MALL before arrival
      if (tid == 0) __hip_atomic_fetch_add(&gc[l * 32], 1u, __ATOMIC_RELAXED, __HIP_MEMORY_SCOPE_AGENT);
    }
  } else {
    float biasr[3];
#pragma unroll
    for (int n = 0; n < 3; ++n) biasr[n] = A.fbias[3 * 2048 + nt * 48 + n * 16 + l15];
    __syncthreads();

    for (int t = 0; t < Tt; ++t) {
      if (tid == 0) wait_ge(&gc[64], 32u * (unsigned)(t + 1));   // h_2(t) ready
      __syncthreads();
      f32x4 acc[3] = {};
      gemm1<32, 512, true, 3, true>(A.hring + (size_t)(16 + (t & 7)) * (Bb * Hh), Hh, wlds, acc);
#pragma unroll
      for (int n = 0; n < 3; ++n)
#pragma unroll
        for (int q = 0; q < 4; ++q) {
          int b = w * 16 + l4 * 4 + q;
          A.out[(b * Tt + t) * Vv + nt * 48 + n * 16 + l15] = acc[n][q] + biasr[n];
        }
      __syncthreads();
      if (tid == 0) __hip_atomic_fetch_add(&gc[96], 1u, __ATOMIC_RELAXED, __HIP_MEMORY_SCOPE_AGENT);
    }
  }
}

extern "C" void kernel_launch(void* const* d_in, const int* in_sizes, int n_in,
                              void* d_out, int out_size, void* d_ws, size_t ws_size,
                              hipStream_t stream) {
  char* base = (char*)d_ws;
  KP a;
  a.x    = (const float*)d_in[0];
  a.h0   = (const float*)d_in[1];
  a.c0   = (const float*)d_in[2];
  a.Wih0 = (const float*)d_in[3];  a.Whh0 = (const float*)d_in[4];
  a.bih0 = (const float*)d_in[5];  a.bhh0 = (const float*)d_in[6];
  a.Wih1 = (const float*)d_in[7];  a.Whh1 = (const float*)d_in[8];
  a.bih1 = (const float*)d_in[9];  a.bhh1 = (const float*)d_in[10];
  a.Wih2 = (const float*)d_in[11]; a.Whh2 = (const float*)d_in[12];
  a.bih2 = (const float*)d_in[13]; a.bhh2 = (const float*)d_in[14];
  a.Wfc  = (const float*)d_in[15]; a.bfc  = (const float*)d_in[16];
  a.out  = (float*)d_out;
  a.bar   = (unsigned*)base;                    // 1 KB flags
  a.fbias = (float*)(base + 1024);              // 24,960 B (pad to 26,624)
  a.wimg  = (_Float16*)(base + 27648);          // 98*131072 = 12,845,056 B
  a.xb    = (_Float16*)(base + 12872704);       // 12,582,912 B
  a.hring = (_Float16*)(base + 25455616);       // 3,145,728 B  (total ~28.6 MB)

  hipMemsetAsync(a.bar, 0, 1024, stream);
  hipLaunchKernelGGL(prologue_kernel, dim3(98), dim3(256), 0, stream, a);
  hipLaunchKernelGGL(lstm_persist, dim3(98), dim3(512), 0, stream, a);
}